// Round 4
// baseline (881.317 us; speedup 1.0000x reference)
//
#include <hip/hip_runtime.h>
#include <cstdint>
#include <cstddef>

#define M_DIM 2048
#define N_DIM 4096
#define K_DIM 20000
#define WBT_BYTES 163840000UL    /* 4096*20000*2 : bf16 W^T (N x K), built in-place */
#define XB_OFFSET 163840000UL    /* bf16 x after Wbt */
#define CP_OFFSET 245760000UL    /* 4x fp32 C-partials after xb */

typedef __attribute__((ext_vector_type(8))) short short8;
typedef __attribute__((ext_vector_type(2))) short short2v;
typedef __attribute__((ext_vector_type(4))) float float4v;
typedef __attribute__((ext_vector_type(8))) unsigned short ushort8;

__device__ __forceinline__ unsigned short f2bf_rne(float f) {
    union { float f; unsigned int u; } v; v.f = f;
    unsigned int u = v.u;
    u += 0x7FFFu + ((u >> 16) & 1u);   // round-to-nearest-even
    return (unsigned short)(u >> 16);
}

__device__ __forceinline__ float bf2f(unsigned short h) {
    union { unsigned int u; float f; } v;
    v.u = ((unsigned int)h) << 16;
    return v.f;
}

__device__ __forceinline__ void gload_lds16(const void* g, void* l) {
    __builtin_amdgcn_global_load_lds(
        (const __attribute__((address_space(1))) void*)g,
        (__attribute__((address_space(3))) void*)l, 16, 0, 0);
}

// ---- 1. scatter-add COO directly into bf16 W^T (N_DIM x K_DIM row-major) ----
// Preferred: HW packed-bf16 atomic add (single fire-and-forget op, no readback).
// Fallback: CAS loop with assumed=0 first guess (no preload round trip).
__global__ void scatter_bf16_kernel(const float* __restrict__ kv,
                                    const int* __restrict__ ind,
                                    unsigned short* __restrict__ W, int nnz) {
    int t = blockIdx.x * blockDim.x + threadIdx.x;
    if (t >= nnz) return;
    int r = ind[2 * t];      // input_dim index (K)
    int c = ind[2 * t + 1];  // units index (N)
    float v = kv[t];
    size_t elem = (size_t)c * K_DIM + r;   // bf16 element index in W^T
    const bool hi = (elem & 1) != 0;       // K_DIM even -> rows never straddle words
#if __has_builtin(__builtin_amdgcn_global_atomic_fadd_v2bf16)
    unsigned short h = f2bf_rne(v);
    short2v val;
    val[0] = hi ? (short)0 : (short)h;
    val[1] = hi ? (short)h : (short)0;
    __builtin_amdgcn_global_atomic_fadd_v2bf16(
        (__attribute__((address_space(1))) short2v*)(W + (elem & ~(size_t)1)), val);
#else
    unsigned int* word = (unsigned int*)(W + (elem & ~(size_t)1));
    unsigned int assumed = 0, old;
    for (;;) {
        unsigned short cur = hi ? (unsigned short)(assumed >> 16)
                                : (unsigned short)(assumed & 0xFFFFu);
        unsigned short nh = f2bf_rne(bf2f(cur) + v);
        unsigned int nw = hi ? ((assumed & 0x0000FFFFu) | ((unsigned int)nh << 16))
                             : ((assumed & 0xFFFF0000u) | (unsigned int)nh);
        old = atomicCAS(word, assumed, nw);
        if (old == assumed) break;
        assumed = old;
    }
#endif
}

// ---- 2. streaming fp32 -> bf16 convert (for x), 8 elements per thread ----
__global__ void convert_kernel(const float* __restrict__ src,
                               unsigned short* __restrict__ dst) {
    size_t t = (size_t)blockIdx.x * 256 + threadIdx.x;
    const float4* sv = (const float4*)src;
    float4 a = sv[2 * t];
    float4 b = sv[2 * t + 1];
    ushort8 o;
    o[0] = f2bf_rne(a.x); o[1] = f2bf_rne(a.y);
    o[2] = f2bf_rne(a.z); o[3] = f2bf_rne(a.w);
    o[4] = f2bf_rne(b.x); o[5] = f2bf_rne(b.y);
    o[6] = f2bf_rne(b.z); o[7] = f2bf_rne(b.w);
    *(ushort8*)(dst + 8 * t) = o;
}

// ---- 3. split-K=4 GEMM partial: Cp[z] = A[:, kz] @ Bt[:, kz]^T (fp32, no epilogue)
// A: MxK bf16 row-major, Bt: NxK bf16 row-major.
// 128x128 block tile, BK=32, 4 waves in 2x2, each wave 64x64 via 4x4 16x16x32 MFMAs.
// 1D grid of 2048 with XCD-affinity decode: the 16 blocks sharing one B-panel
// (same n-tile bx, same K-slice z) get identical id%8 (-> same XCD under the
// round-robin heuristic) and adjacent dispatch slots -> B-panel L2-resident.
__global__ __launch_bounds__(256) void gemm_bt_partial_kernel(
    const unsigned short* __restrict__ A,
    const unsigned short* __restrict__ Bt,
    float* __restrict__ Cp) {

    __shared__ unsigned short Als[128 * 32];   // [m][k], row = 64 B
    __shared__ unsigned short Bls[128 * 32];   // [n][k]

    const int id  = blockIdx.x;
    const int xcd = id & 7;
    const int q   = id >> 3;
    const int y   = q & 15;          // M tile (16)
    const int ghi = q >> 4;          // 0..15
    const int g   = xcd + 8 * ghi;   // B-panel group 0..127
    const int bx  = g & 31;          // N tile (32)
    const int z   = g >> 5;          // K slice (4)

    const int t    = threadIdx.x;
    const int wid  = t >> 6;
    const int lane = t & 63;
    const int quad = lane >> 4;
    const int r16  = lane & 15;
    const int wm   = wid >> 1;
    const int wn   = wid & 1;

    const int m0 = y * 128;
    const int n0 = bx * 128;
    const int iters = z ? 156 : 157;              // sum 625 = 20000/32
    const int k0 = (z ? (157 + 156 * (z - 1)) : 0) * 32;

    const unsigned short* gA0 = A  + (size_t)(m0 + (t >> 2)) * K_DIM + (t & 3) * 8 + k0;
    const unsigned short* gA1 = gA0 + (size_t)64 * K_DIM;
    const unsigned short* gB0 = Bt + (size_t)(n0 + (t >> 2)) * K_DIM + (t & 3) * 8 + k0;
    const unsigned short* gB1 = gB0 + (size_t)64 * K_DIM;

    char* lA0 = (char*)Als + wid * 1024;          // wave-uniform bases
    char* lA1 = (char*)Als + 4096 + wid * 1024;
    char* lB0 = (char*)Bls + wid * 1024;
    char* lB1 = (char*)Bls + 4096 + wid * 1024;

    const int abase = (wm * 64 + r16) * 64 + quad * 16;
    const int bbase = (wn * 64 + r16) * 64 + quad * 16;

    float4v acc[4][4];
    #pragma unroll
    for (int i = 0; i < 4; ++i)
        #pragma unroll
        for (int j = 0; j < 4; ++j)
            acc[i][j] = (float4v){0.f, 0.f, 0.f, 0.f};

    for (int kt = 0; kt < iters; ++kt) {
        gload_lds16(gA0, lA0);
        gload_lds16(gA1, lA1);
        gload_lds16(gB0, lB0);
        gload_lds16(gB1, lB1);
        gA0 += 32; gA1 += 32; gB0 += 32; gB1 += 32;
        __syncthreads();

        short8 af[4], bfr[4];
        #pragma unroll
        for (int i = 0; i < 4; ++i)
            af[i] = *(const short8*)((const char*)Als + abase + i * 1024);
        #pragma unroll
        for (int j = 0; j < 4; ++j)
            bfr[j] = *(const short8*)((const char*)Bls + bbase + j * 1024);

        #pragma unroll
        for (int i = 0; i < 4; ++i)
            #pragma unroll
            for (int j = 0; j < 4; ++j)
                acc[i][j] = __builtin_amdgcn_mfma_f32_16x16x32_bf16(
                    af[i], bfr[j], acc[i][j], 0, 0, 0);
        __syncthreads();
    }

    // write raw fp32 partial; C/D layout: col = lane&15, row = quad*4 + reg
    float* Cz = Cp + (size_t)z * M_DIM * N_DIM;
    #pragma unroll
    for (int i = 0; i < 4; ++i) {
        const int row = m0 + wm * 64 + i * 16 + quad * 4;
        #pragma unroll
        for (int j = 0; j < 4; ++j) {
            const int col = n0 + wn * 64 + j * 16 + r16;
            #pragma unroll
            for (int r = 0; r < 4; ++r)
                Cz[(size_t)(row + r) * N_DIM + col] = acc[i][j][r];
        }
    }
}

// ---- 4. combine: out = tanh(C0 + C1 + C2 + C3 + bias), float4 vectorized ----
__global__ void combine_kernel(const float* __restrict__ Cp,
                               const float* __restrict__ bias,
                               float* __restrict__ out) {
    size_t t = (size_t)blockIdx.x * 256 + threadIdx.x;       // per float4
    const size_t stride = (size_t)M_DIM * N_DIM / 4;
    float4 a = ((const float4*)Cp)[t];
    float4 b = ((const float4*)Cp)[t + stride];
    float4 c = ((const float4*)Cp)[t + 2 * stride];
    float4 d = ((const float4*)Cp)[t + 3 * stride];
    float4 bv = ((const float4*)bias)[t & (N_DIM / 4 - 1)];
    float4 o;
    o.x = tanhf(a.x + b.x + c.x + d.x + bv.x);
    o.y = tanhf(a.y + b.y + c.y + d.y + bv.y);
    o.z = tanhf(a.z + b.z + c.z + d.z + bv.z);
    o.w = tanhf(a.w + b.w + c.w + d.w + bv.w);
    ((float4*)out)[t] = o;
}

extern "C" void kernel_launch(void* const* d_in, const int* in_sizes, int n_in,
                              void* d_out, int out_size, void* d_ws, size_t ws_size,
                              hipStream_t stream) {
    const float* x    = (const float*)d_in[0];
    const float* kv   = (const float*)d_in[1];
    const float* bias = (const float*)d_in[2];
    const int*   ind  = (const int*)d_in[3];
    const int nnz = in_sizes[1];

    unsigned short* Wbt = (unsigned short*)d_ws;                        // 163.84 MB bf16 W^T
    unsigned short* xb  = (unsigned short*)((char*)d_ws + XB_OFFSET);   // 81.92 MB bf16 x
    float* Cp = (float*)((char*)d_ws + CP_OFFSET);                      // 4 x 33.55 MB partials

    // 1. zero bf16 W^T
    hipMemsetAsync(Wbt, 0, WBT_BYTES, stream);
    // 2. scatter-add straight into bf16 W^T (HW packed-bf16 atomic)
    scatter_bf16_kernel<<<(nnz + 255) / 256, 256, 0, stream>>>(
        kv, ind, Wbt, nnz);
    // 3. x fp32 -> bf16
    convert_kernel<<<(M_DIM * K_DIM) / (256 * 8), 256, 0, stream>>>(x, xb);
    // 4. split-K=4 GEMM partials, XCD-swizzled 1D grid
    gemm_bt_partial_kernel<<<2048, 256, 0, stream>>>(xb, Wbt, Cp);
    // 5. combine + bias + tanh
    combine_kernel<<<(M_DIM * N_DIM) / (256 * 4), 256, 0, stream>>>(
        Cp, bias, (float*)d_out);
}